// Round 3
// baseline (1135.260 us; speedup 1.0000x reference)
//
#include <hip/hip_runtime.h>
#include <hip/hip_bf16.h>
#include <math.h>

// Bucketed GCN: bucket = dst >> 7 (128 nodes/bucket). Edges grouped by bucket
// once, then each layer aggregates block-per-bucket into LDS (ds_add_f32),
// with the dense layer fused into the epilogue.

#define BW   128      // nodes per bucket
#define BSH  7        // log2(BW)
#define MAXBUK 1024   // supports n <= 131072

static inline int cdiv(int a, int b) { return (a + b - 1) / b; }

// ---------------- bucket build ----------------

__global__ void __launch_bounds__(256) k_bhist(const int* __restrict__ dst,
                                               int* __restrict__ bcnt, int e, int nbuk) {
    __shared__ int lh[MAXBUK];
    for (int b = threadIdx.x; b < nbuk; b += 256) lh[b] = 0;
    __syncthreads();
    int base = blockIdx.x * 4096;
#pragma unroll
    for (int j = 0; j < 16; j++) {
        int i = base + j * 256 + threadIdx.x;
        if (i < e) atomicAdd(&lh[dst[i] >> BSH], 1);
    }
    __syncthreads();
    for (int b = threadIdx.x; b < nbuk; b += 256) {
        int c = lh[b];
        if (c) atomicAdd(&bcnt[b], c);
    }
}

__global__ void __launch_bounds__(1024) k_bscan(const int* __restrict__ bcnt,
                                                int* __restrict__ boff, int* __restrict__ gcur,
                                                int nbuk, int e) {
    __shared__ int sh[1024];
    int t = threadIdx.x;
    int v = (t < nbuk) ? bcnt[t] : 0;
    sh[t] = v;
    __syncthreads();
    for (int o = 1; o < 1024; o <<= 1) {
        int u = (t >= o) ? sh[t - o] : 0;
        __syncthreads();
        sh[t] += u;
        __syncthreads();
    }
    if (t < nbuk) { int ex = sh[t] - v; boff[t] = ex; gcur[t] = ex; }
    if (t == 0) boff[nbuk] = e;
}

__global__ void __launch_bounds__(256) k_bscatter(const int* __restrict__ src,
                                                  const int* __restrict__ dst,
                                                  int* __restrict__ gcur,
                                                  int2* __restrict__ ebuf, int e, int nbuk) {
    __shared__ int lh[MAXBUK];
    __shared__ int lb[MAXBUK];
    for (int b = threadIdx.x; b < nbuk; b += 256) lh[b] = 0;
    __syncthreads();
    int base = blockIdx.x * 8192;
#pragma unroll
    for (int j = 0; j < 32; j++) {
        int i = base + j * 256 + threadIdx.x;
        if (i < e) atomicAdd(&lh[dst[i] >> BSH], 1);
    }
    __syncthreads();
    for (int b = threadIdx.x; b < nbuk; b += 256) {
        int c = lh[b];
        lb[b] = c ? atomicAdd(&gcur[b], c) : 0;
        lh[b] = 0;
    }
    __syncthreads();
#pragma unroll
    for (int j = 0; j < 32; j++) {
        int i = base + j * 256 + threadIdx.x;
        if (i < e) {
            int d = dst[i], s = src[i];
            int b = d >> BSH;
            int r = atomicAdd(&lh[b], 1);
            ebuf[lb[b] + r] = make_int2(d, s);
        }
    }
}

// ---------------- degree / dinv / pre-scale ----------------

__global__ void __launch_bounds__(256) k_dinvB(const int2* __restrict__ ebuf,
                                               const int* __restrict__ boff,
                                               float* __restrict__ dinv, int n) {
    __shared__ int cnt[BW];
    if (threadIdx.x < BW) cnt[threadIdx.x] = 0;
    __syncthreads();
    int beg = boff[blockIdx.x], end = boff[blockIdx.x + 1];
    for (int k = beg + threadIdx.x; k < end; k += 256)
        atomicAdd(&cnt[ebuf[k].x & (BW - 1)], 1);
    __syncthreads();
    int node = blockIdx.x * BW + threadIdx.x;
    if (threadIdx.x < BW && node < n)
        dinv[node] = rsqrtf((float)cnt[threadIdx.x] + 1.0f);
}

// xs[i][f] = x[i][f] * dinv[i]   (16-dim, float4 chunks)
__global__ void __launch_bounds__(256) k_xscale(const float* __restrict__ x,
                                                const float* __restrict__ dinv,
                                                float* __restrict__ xs, int n4) {
    int i = blockIdx.x * blockDim.x + threadIdx.x;
    if (i >= n4) return;
    float dd = dinv[i >> 2];
    float4 v = ((const float4*)x)[i];
    v.x *= dd; v.y *= dd; v.z *= dd; v.w *= dd;
    ((float4*)xs)[i] = v;
}

// ---------------- layer 1: agg(xs,16) -> dense 16->32 relu -> h1s = h1*dinv ----------------

__global__ void __launch_bounds__(256) k_aggL1(const int2* __restrict__ ebuf,
                                               const int* __restrict__ boff,
                                               const float* __restrict__ dinv,
                                               const float* __restrict__ xs,
                                               const float* __restrict__ W1,
                                               const float* __restrict__ b1,
                                               float* __restrict__ h1s, int n) {
    __shared__ float acc[BW * 17];
    __shared__ float sW[16 * 32];
    __shared__ float sb[32];
    for (int i = threadIdx.x; i < BW * 17; i += 256) acc[i] = 0.f;
    for (int i = threadIdx.x; i < 512; i += 256) sW[i] = W1[i];
    if (threadIdx.x < 32) sb[threadIdx.x] = b1[threadIdx.x];
    __syncthreads();
    int beg = boff[blockIdx.x], end = boff[blockIdx.x + 1];
    const float4* x4 = (const float4*)xs;
    for (int k = beg + threadIdx.x; k < end; k += 256) {
        int2 eg = ebuf[k];
        int dl = eg.x & (BW - 1);
        size_t s = (size_t)eg.y;
#pragma unroll
        for (int f = 0; f < 4; f++) {
            float4 v = x4[s * 4 + f];
            float* a = &acc[dl * 17 + f * 4];
            atomicAdd(a + 0, v.x); atomicAdd(a + 1, v.y);
            atomicAdd(a + 2, v.z); atomicAdd(a + 3, v.w);
        }
    }
    __syncthreads();
    int nbase = blockIdx.x * BW;
    // phase A: full_agg = (acc + xs[node]) * dinv[node]
    for (int it = threadIdx.x; it < BW * 4; it += 256) {
        int nl = it >> 2, f = it & 3;
        int node = nbase + nl;
        if (node < n) {
            float dd = dinv[node];
            float4 v = x4[(size_t)node * 4 + f];
            float* a = &acc[nl * 17 + f * 4];
            a[0] = (a[0] + v.x) * dd;
            a[1] = (a[1] + v.y) * dd;
            a[2] = (a[2] + v.z) * dd;
            a[3] = (a[3] + v.w) * dd;
        }
    }
    __syncthreads();
    // phase B: h1s[node] = relu(full_agg @ W1 + b1) * dinv[node]
    float4* h14 = (float4*)h1s;
    for (int it = threadIdx.x; it < BW * 8; it += 256) {
        int nl = it >> 3, f4 = it & 7;
        int node = nbase + nl;
        if (node < n) {
            float dd = dinv[node];
            const float* a = &acc[nl * 17];
            float o0 = sb[f4 * 4 + 0], o1 = sb[f4 * 4 + 1], o2 = sb[f4 * 4 + 2], o3 = sb[f4 * 4 + 3];
#pragma unroll
            for (int k2 = 0; k2 < 16; k2++) {
                float av = a[k2];
                const float* w = &sW[k2 * 32 + f4 * 4];
                o0 += av * w[0]; o1 += av * w[1]; o2 += av * w[2]; o3 += av * w[3];
            }
            float4 ov;
            ov.x = fmaxf(o0, 0.f) * dd; ov.y = fmaxf(o1, 0.f) * dd;
            ov.z = fmaxf(o2, 0.f) * dd; ov.w = fmaxf(o3, 0.f) * dd;
            h14[(size_t)node * 8 + f4] = ov;
        }
    }
}

// ---------------- layer 2: agg(h1s,32) -> dense 32->64 relu -> dot W3 -> t2 = t*dinv ----------------

__global__ void __launch_bounds__(256) k_aggL2(const int2* __restrict__ ebuf,
                                               const int* __restrict__ boff,
                                               const float* __restrict__ dinv,
                                               const float* __restrict__ h1s,
                                               const float* __restrict__ W2,
                                               const float* __restrict__ b2,
                                               const float* __restrict__ W3,
                                               float* __restrict__ t2, int n) {
    __shared__ float acc[BW * 33];   // 16.9 KB
    __shared__ float sW[32 * 64];    // 8 KB
    __shared__ float sb[64];
    __shared__ float sw3[64];
    __shared__ float part[BW * 4];
    for (int i = threadIdx.x; i < BW * 33; i += 256) acc[i] = 0.f;
    for (int i = threadIdx.x; i < 2048; i += 256) sW[i] = W2[i];
    if (threadIdx.x < 64) { sb[threadIdx.x] = b2[threadIdx.x]; sw3[threadIdx.x] = W3[threadIdx.x]; }
    __syncthreads();
    int beg = boff[blockIdx.x], end = boff[blockIdx.x + 1];
    const float4* h4 = (const float4*)h1s;
    for (int k = beg + threadIdx.x; k < end; k += 256) {
        int2 eg = ebuf[k];
        int dl = eg.x & (BW - 1);
        size_t s = (size_t)eg.y;
#pragma unroll
        for (int f = 0; f < 8; f++) {
            float4 v = h4[s * 8 + f];
            float* a = &acc[dl * 33 + f * 4];
            atomicAdd(a + 0, v.x); atomicAdd(a + 1, v.y);
            atomicAdd(a + 2, v.z); atomicAdd(a + 3, v.w);
        }
    }
    __syncthreads();
    int nbase = blockIdx.x * BW;
    // phase A: full_agg = (acc + h1s[node]) * dinv[node]
    for (int it = threadIdx.x; it < BW * 8; it += 256) {
        int nl = it >> 3, f = it & 7;
        int node = nbase + nl;
        if (node < n) {
            float dd = dinv[node];
            float4 v = h4[(size_t)node * 8 + f];
            float* a = &acc[nl * 33 + f * 4];
            a[0] = (a[0] + v.x) * dd;
            a[1] = (a[1] + v.y) * dd;
            a[2] = (a[2] + v.z) * dd;
            a[3] = (a[3] + v.w) * dd;
        }
    }
    __syncthreads();
    // phase B: partial dot over 16-col groups of relu(full_agg @ W2 + b2) with W3
    for (int it = threadIdx.x; it < BW * 4; it += 256) {
        int nl = it >> 2, c16 = it & 3;
        const float* a = &acc[nl * 33];
        float p = 0.f;
#pragma unroll
        for (int cc = 0; cc < 16; cc++) {
            int col = c16 * 16 + cc;
            float o = sb[col];
#pragma unroll
            for (int k2 = 0; k2 < 32; k2++) o += a[k2] * sW[k2 * 64 + col];
            p += fmaxf(o, 0.f) * sw3[col];
        }
        part[nl * 4 + c16] = p;
    }
    __syncthreads();
    // phase C: t2[node] = t * dinv[node]
    if (threadIdx.x < BW) {
        int node = nbase + threadIdx.x;
        if (node < n) {
            float t = part[threadIdx.x * 4 + 0] + part[threadIdx.x * 4 + 1] +
                      part[threadIdx.x * 4 + 2] + part[threadIdx.x * 4 + 3];
            t2[node] = t * dinv[node];
        }
    }
}

// ---------------- layer 3: agg(t2,1) + bias + sigmoid ----------------

__global__ void __launch_bounds__(256) k_aggL3(const int2* __restrict__ ebuf,
                                               const int* __restrict__ boff,
                                               const float* __restrict__ dinv,
                                               const float* __restrict__ t2,
                                               const float* __restrict__ b3,
                                               float* __restrict__ out, int n) {
    __shared__ float acc[BW];
    if (threadIdx.x < BW) acc[threadIdx.x] = 0.f;
    __syncthreads();
    int beg = boff[blockIdx.x], end = boff[blockIdx.x + 1];
    for (int k = beg + threadIdx.x; k < end; k += 256) {
        int2 eg = ebuf[k];
        atomicAdd(&acc[eg.x & (BW - 1)], t2[eg.y]);
    }
    __syncthreads();
    int node = blockIdx.x * BW + threadIdx.x;
    if (threadIdx.x < BW && node < n) {
        float dd = dinv[node];
        float v = (acc[threadIdx.x] + t2[node]) * dd + b3[0];
        out[node] = 1.0f / (1.0f + expf(-v));
    }
}

// ---------------- launch ----------------

extern "C" void kernel_launch(void* const* d_in, const int* in_sizes, int n_in,
                              void* d_out, int out_size, void* d_ws, size_t ws_size,
                              hipStream_t stream) {
    const float* x  = (const float*)d_in[0];
    const int*   ei = (const int*)d_in[1];
    const float* W1 = (const float*)d_in[2];
    const float* b1 = (const float*)d_in[3];
    const float* W2 = (const float*)d_in[4];
    const float* b2 = (const float*)d_in[5];
    const float* W3 = (const float*)d_in[6];
    const float* b3 = (const float*)d_in[7];

    const int n = in_sizes[0] / 16;
    const int e = in_sizes[1] / 2;
    const int* src = ei;
    const int* dst = ei + e;
    const int nbuk = cdiv(n, BW);   // 782 for n=100000, <= MAXBUK

    // workspace (4-byte elems, regions padded to 64B)
    auto rup = [](size_t v) { return (v + 15) & ~(size_t)15; };
    char* wp = (char*)d_ws;
    auto alloc = [&](size_t elems) { void* p = wp; wp += rup(elems) * 4; return p; };
    int*   bcnt = (int*)  alloc(MAXBUK);
    int*   boff = (int*)  alloc(MAXBUK + 1);
    int*   gcur = (int*)  alloc(MAXBUK);
    float* dinv = (float*)alloc(n);
    float* xs   = (float*)alloc((size_t)16 * n);
    int2*  ebuf = (int2*) alloc((size_t)2 * e);
    float* h1s  = (float*)alloc((size_t)32 * n);
    float* t2   = (float*)alloc(n);

    float* out = (float*)d_out;
    const int B = 256;

    hipMemsetAsync(bcnt, 0, MAXBUK * 4, stream);
    k_bhist<<<cdiv(e, 4096), B, 0, stream>>>(dst, bcnt, e, nbuk);
    k_bscan<<<1, 1024, 0, stream>>>(bcnt, boff, gcur, nbuk, e);
    k_bscatter<<<cdiv(e, 8192), B, 0, stream>>>(src, dst, gcur, ebuf, e, nbuk);
    k_dinvB<<<nbuk, B, 0, stream>>>(ebuf, boff, dinv, n);
    k_xscale<<<cdiv(n * 4, B), B, 0, stream>>>(x, dinv, xs, n * 4);

    k_aggL1<<<nbuk, B, 0, stream>>>(ebuf, boff, dinv, xs, W1, b1, h1s, n);
    k_aggL2<<<nbuk, B, 0, stream>>>(ebuf, boff, dinv, h1s, W2, b2, W3, t2, n);
    k_aggL3<<<nbuk, B, 0, stream>>>(ebuf, boff, dinv, t2, b3, out, n);
}

// Round 4
// 255.487 us; speedup vs baseline: 4.4435x; 4.4435x over previous
//
#include <hip/hip_runtime.h>
#include <hip/hip_bf16.h>
#include <math.h>

// GCN, hybrid scheme:
//   1) bucket sort edges by dst>>7 (LDS-aggregated, chunked coalesced writes)
//   2) per-bucket exact CSR (LDS hist+scan+scatter within 16KB window)
//   3) wave-per-node pull aggregation (no atomics, huge TLP)
// Features pre-scaled by dinv[src]; dense layers fused into epilogues.

#define BW    128     // nodes per bucket
#define BSH   7
#define MAXBUK 1024   // n <= 131072 (packing uses 17 bits for src)

static inline int cdiv(int a, int b) { return (a + b - 1) / b; }

// ---------------- bucket build ----------------

__global__ void __launch_bounds__(256) k_bhist(const int* __restrict__ dst,
                                               int* __restrict__ bcnt, int e, int nbuk) {
    __shared__ int lh[MAXBUK];
    for (int b = threadIdx.x; b < nbuk; b += 256) lh[b] = 0;
    __syncthreads();
    int base = blockIdx.x * 4096;
#pragma unroll
    for (int j = 0; j < 16; j++) {
        int i = base + j * 256 + threadIdx.x;
        if (i < e) atomicAdd(&lh[dst[i] >> BSH], 1);
    }
    __syncthreads();
    for (int b = threadIdx.x; b < nbuk; b += 256) {
        int c = lh[b];
        if (c) atomicAdd(&bcnt[b], c);
    }
}

__global__ void __launch_bounds__(1024) k_bscan(const int* __restrict__ bcnt,
                                                int* __restrict__ boff, int* __restrict__ gcur,
                                                int nbuk, int e) {
    __shared__ int sh[1024];
    int t = threadIdx.x;
    int v = (t < nbuk) ? bcnt[t] : 0;
    sh[t] = v;
    __syncthreads();
    for (int o = 1; o < 1024; o <<= 1) {
        int u = (t >= o) ? sh[t - o] : 0;
        __syncthreads();
        sh[t] += u;
        __syncthreads();
    }
    if (t < nbuk) { int ex = sh[t] - v; boff[t] = ex; gcur[t] = ex; }
    if (t == 0) boff[nbuk] = e;
}

// pack (dstLocal<<17)|src into one int
__global__ void __launch_bounds__(256) k_bscatter(const int* __restrict__ src,
                                                  const int* __restrict__ dst,
                                                  int* __restrict__ gcur,
                                                  int* __restrict__ ebuf, int e, int nbuk) {
    __shared__ int lh[MAXBUK];
    __shared__ int lb[MAXBUK];
    for (int b = threadIdx.x; b < nbuk; b += 256) lh[b] = 0;
    __syncthreads();
    int base = blockIdx.x * 8192;
#pragma unroll
    for (int j = 0; j < 32; j++) {
        int i = base + j * 256 + threadIdx.x;
        if (i < e) atomicAdd(&lh[dst[i] >> BSH], 1);
    }
    __syncthreads();
    for (int b = threadIdx.x; b < nbuk; b += 256) {
        int c = lh[b];
        lb[b] = c ? atomicAdd(&gcur[b], c) : 0;
        lh[b] = 0;
    }
    __syncthreads();
#pragma unroll
    for (int j = 0; j < 32; j++) {
        int i = base + j * 256 + threadIdx.x;
        if (i < e) {
            int d = dst[i], s = src[i];
            int b = d >> BSH;
            int r = atomicAdd(&lh[b], 1);
            ebuf[lb[b] + r] = ((d & (BW - 1)) << 17) | s;
        }
    }
}

// ---------------- per-bucket exact CSR + dinv ----------------

__global__ void __launch_bounds__(256) k_csr(const int* __restrict__ ebuf,
                                             const int* __restrict__ boff,
                                             int* __restrict__ rowstart,
                                             int* __restrict__ csr_src,
                                             float* __restrict__ dinv, int n, int e) {
    __shared__ int cnt[BW];
    __shared__ int offs[BW];
    int t = threadIdx.x;
    if (t < BW) cnt[t] = 0;
    __syncthreads();
    int beg = boff[blockIdx.x], end = boff[blockIdx.x + 1];
    for (int k = beg + t; k < end; k += 256)
        atomicAdd(&cnt[ebuf[k] >> 17], 1);
    __syncthreads();
    int v = (t < BW) ? cnt[t] : 0;
    if (t < BW) offs[t] = v;
    __syncthreads();
    for (int o = 1; o < BW; o <<= 1) {
        int u = (t < BW && t >= o) ? offs[t - o] : 0;
        __syncthreads();
        if (t < BW) offs[t] += u;
        __syncthreads();
    }
    int nbase = blockIdx.x * BW;
    if (t < BW) {
        int ex = offs[t] - v;               // exclusive
        int node = nbase + t;
        if (node < n) {
            rowstart[node] = beg + ex;
            dinv[node] = rsqrtf((float)v + 1.0f);
        }
        cnt[t] = ex;                        // reuse as cursor
    }
    __syncthreads();
    for (int k = beg + t; k < end; k += 256) {
        int pv = ebuf[k];
        int dl = pv >> 17, s = pv & 0x1FFFF;
        int r = atomicAdd(&cnt[dl], 1);
        csr_src[beg + r] = s;
    }
    if (blockIdx.x == 0 && t == 0) rowstart[n] = e;
}

// ---------------- pre-scale ----------------

__global__ void __launch_bounds__(256) k_xscale(const float* __restrict__ x,
                                                const float* __restrict__ dinv,
                                                float* __restrict__ xs, int n4) {
    int i = blockIdx.x * blockDim.x + threadIdx.x;
    if (i >= n4) return;
    float dd = dinv[i >> 2];
    float4 v = ((const float4*)x)[i];
    v.x *= dd; v.y *= dd; v.z *= dd; v.w *= dd;
    ((float4*)xs)[i] = v;
}

// ---------------- pull aggregation (feat pre-scaled by dinv[src]) ----------------
// out[i] = dinv[i] * ( sum_{s in N(i)} feat_s[s]  +  feat_s[i] )

template<int D, int LOGD>
__global__ void __launch_bounds__(256) k_pull(const int* __restrict__ rowstart,
                                              const int* __restrict__ csr_src,
                                              const float* __restrict__ dinv,
                                              const float* __restrict__ feat_s,
                                              float* __restrict__ out, int n) {
    constexpr int NV4 = D / 4;
    constexpr int LOGNV4 = LOGD - 2;
    constexpr int EPI = 64 >> LOGNV4;
    int wid = (blockIdx.x * blockDim.x + threadIdx.x) >> 6;
    if (wid >= n) return;
    int lane = threadIdx.x & 63;
    int f4 = lane & (NV4 - 1);
    int j = lane >> LOGNV4;
    int beg = rowstart[wid], end = rowstart[wid + 1];
    const float4* feat4 = (const float4*)feat_s;
    float4 acc = make_float4(0.f, 0.f, 0.f, 0.f);
    for (int k = beg + j; k < end; k += EPI) {
        int s = csr_src[k];
        float4 v = feat4[(size_t)s * NV4 + f4];
        acc.x += v.x; acc.y += v.y; acc.z += v.z; acc.w += v.w;
    }
    for (int off = NV4; off < 64; off <<= 1) {
        acc.x += __shfl_xor(acc.x, off);
        acc.y += __shfl_xor(acc.y, off);
        acc.z += __shfl_xor(acc.z, off);
        acc.w += __shfl_xor(acc.w, off);
    }
    if (lane < NV4) {
        float dd = dinv[wid];
        float4 sv = feat4[(size_t)wid * NV4 + lane];
        float4 o;
        o.x = (acc.x + sv.x) * dd;
        o.y = (acc.y + sv.y) * dd;
        o.z = (acc.z + sv.z) * dd;
        o.w = (acc.w + sv.w) * dd;
        ((float4*)out)[(size_t)wid * NV4 + lane] = o;
    }
}

// final layer: scalar pull over t2 + bias + sigmoid
__global__ void __launch_bounds__(256) k_pull1_sig(const int* __restrict__ rowstart,
                                                   const int* __restrict__ csr_src,
                                                   const float* __restrict__ dinv,
                                                   const float* __restrict__ t2,
                                                   const float* __restrict__ b3,
                                                   float* __restrict__ out, int n) {
    int wid = (blockIdx.x * blockDim.x + threadIdx.x) >> 6;
    if (wid >= n) return;
    int lane = threadIdx.x & 63;
    int beg = rowstart[wid], end = rowstart[wid + 1];
    float acc = 0.f;
    for (int k = beg + lane; k < end; k += 64) acc += t2[csr_src[k]];
    for (int off = 1; off < 64; off <<= 1) acc += __shfl_xor(acc, off);
    if (lane == 0) {
        float v = (acc + t2[wid]) * dinv[wid] + b3[0];
        out[wid] = 1.0f / (1.0f + expf(-v));
    }
}

// ---------------- dense layers (fused scaling) ----------------

// h1s = relu(agg @ W1 + b1) * dinv     (16 -> 32)
__global__ void __launch_bounds__(256) k_dense1(const float* __restrict__ agg,
                                                const float* __restrict__ W1,
                                                const float* __restrict__ b1,
                                                const float* __restrict__ dinv,
                                                float* __restrict__ h1s, int n) {
    __shared__ float sW[512];
    __shared__ float sb[32];
    for (int i = threadIdx.x; i < 512; i += 256) sW[i] = W1[i];
    if (threadIdx.x < 32) sb[threadIdx.x] = b1[threadIdx.x];
    __syncthreads();
    int node = blockIdx.x * 256 + threadIdx.x;
    if (node >= n) return;
    float in[16];
    const float4* a4 = (const float4*)(agg + (size_t)node * 16);
#pragma unroll
    for (int f = 0; f < 4; f++) {
        float4 v = a4[f];
        in[f * 4 + 0] = v.x; in[f * 4 + 1] = v.y; in[f * 4 + 2] = v.z; in[f * 4 + 3] = v.w;
    }
    float dd = dinv[node];
    float4* o4 = (float4*)(h1s + (size_t)node * 32);
#pragma unroll
    for (int f4 = 0; f4 < 8; f4++) {
        float o0 = sb[f4 * 4 + 0], o1 = sb[f4 * 4 + 1], o2 = sb[f4 * 4 + 2], o3 = sb[f4 * 4 + 3];
#pragma unroll
        for (int k = 0; k < 16; k++) {
            float av = in[k];
            const float* w = &sW[k * 32 + f4 * 4];
            o0 += av * w[0]; o1 += av * w[1]; o2 += av * w[2]; o3 += av * w[3];
        }
        float4 ov;
        ov.x = fmaxf(o0, 0.f) * dd; ov.y = fmaxf(o1, 0.f) * dd;
        ov.z = fmaxf(o2, 0.f) * dd; ov.w = fmaxf(o3, 0.f) * dd;
        o4[f4] = ov;
    }
}

// t2 = (relu(agg @ W2 + b2) @ W3) * dinv    (32 -> 64 -> 1)
__global__ void __launch_bounds__(256) k_dense2(const float* __restrict__ agg,
                                                const float* __restrict__ W2,
                                                const float* __restrict__ b2,
                                                const float* __restrict__ W3,
                                                const float* __restrict__ dinv,
                                                float* __restrict__ t2, int n) {
    __shared__ float sW[2048];
    __shared__ float sb[64];
    __shared__ float sw3[64];
    for (int i = threadIdx.x; i < 2048; i += 256) sW[i] = W2[i];
    if (threadIdx.x < 64) { sb[threadIdx.x] = b2[threadIdx.x]; sw3[threadIdx.x] = W3[threadIdx.x]; }
    __syncthreads();
    int node = blockIdx.x * 256 + threadIdx.x;
    if (node >= n) return;
    float in[32];
    const float4* a4 = (const float4*)(agg + (size_t)node * 32);
#pragma unroll
    for (int f = 0; f < 8; f++) {
        float4 v = a4[f];
        in[f * 4 + 0] = v.x; in[f * 4 + 1] = v.y; in[f * 4 + 2] = v.z; in[f * 4 + 3] = v.w;
    }
    float p = 0.f;
#pragma unroll
    for (int col = 0; col < 64; col++) {
        float o = sb[col];
#pragma unroll
        for (int k = 0; k < 32; k++) o += in[k] * sW[k * 64 + col];
        p += fmaxf(o, 0.f) * sw3[col];
    }
    t2[node] = p * dinv[node];
}

// ---------------- launch ----------------

extern "C" void kernel_launch(void* const* d_in, const int* in_sizes, int n_in,
                              void* d_out, int out_size, void* d_ws, size_t ws_size,
                              hipStream_t stream) {
    const float* x  = (const float*)d_in[0];
    const int*   ei = (const int*)d_in[1];
    const float* W1 = (const float*)d_in[2];
    const float* b1 = (const float*)d_in[3];
    const float* W2 = (const float*)d_in[4];
    const float* b2 = (const float*)d_in[5];
    const float* W3 = (const float*)d_in[6];
    const float* b3 = (const float*)d_in[7];

    const int n = in_sizes[0] / 16;
    const int e = in_sizes[1] / 2;
    const int* src = ei;
    const int* dst = ei + e;
    const int nbuk = cdiv(n, BW);   // 782 for n=100000

    auto rup = [](size_t v) { return (v + 15) & ~(size_t)15; };
    char* wp = (char*)d_ws;
    auto alloc = [&](size_t elems) { void* p = wp; wp += rup(elems) * 4; return p; };
    int*   bcnt     = (int*)  alloc(MAXBUK);
    int*   boff     = (int*)  alloc(MAXBUK + 1);
    int*   gcur     = (int*)  alloc(MAXBUK);
    float* dinv     = (float*)alloc(n);
    int*   rowstart = (int*)  alloc(n + 1);
    int*   ebuf     = (int*)  alloc(e);
    int*   csr_src  = (int*)  alloc(e);
    float* xs       = (float*)alloc((size_t)16 * n);
    float* bufA     = (float*)alloc((size_t)32 * n);
    float* h1s      = (float*)alloc((size_t)32 * n);
    float* t2       = (float*)alloc(n);

    float* out = (float*)d_out;
    const int B = 256;
    const int pullGrid = cdiv(n * 64, B);

    hipMemsetAsync(bcnt, 0, MAXBUK * 4, stream);
    k_bhist<<<cdiv(e, 4096), B, 0, stream>>>(dst, bcnt, e, nbuk);
    k_bscan<<<1, 1024, 0, stream>>>(bcnt, boff, gcur, nbuk, e);
    k_bscatter<<<cdiv(e, 8192), B, 0, stream>>>(src, dst, gcur, ebuf, e, nbuk);
    k_csr<<<nbuk, B, 0, stream>>>(ebuf, boff, rowstart, csr_src, dinv, n, e);
    k_xscale<<<cdiv(n * 4, B), B, 0, stream>>>(x, dinv, xs, n * 4);

    // Layer 1
    k_pull<16, 4><<<pullGrid, B, 0, stream>>>(rowstart, csr_src, dinv, xs, bufA, n);
    k_dense1<<<cdiv(n, B), B, 0, stream>>>(bufA, W1, b1, dinv, h1s, n);

    // Layer 2 (+ W3 dot fused)
    k_pull<32, 5><<<pullGrid, B, 0, stream>>>(rowstart, csr_src, dinv, h1s, bufA, n);
    k_dense2<<<cdiv(n, B), B, 0, stream>>>(bufA, W2, b2, W3, dinv, t2, n);

    // Layer 3
    k_pull1_sig<<<pullGrid, B, 0, stream>>>(rowstart, csr_src, dinv, t2, b3, out, n);
}